// Round 2
// baseline (224.907 us; speedup 1.0000x reference)
//
#include <hip/hip_runtime.h>
#include <math.h>
#include <complex>

#define T_STEPS 16384
#define BATCH   512
#define KF      5
#define TAU     (T_STEPS + KF - 1)   /* 16388 */
#define NCHUNK  256
#define CHLEN   (T_STEPS / NCHUNK)   /* 64 */

struct Coefs {
    double b0, b1, b2, b3, b4;   /* FIR numerator */
    double c0, c1, c2, c3;       /* a_rev[:-1] = [a4,a3,a2,a1] */
};

/* ---- K1: per-tau batch mean of padded signal -> noise_sd[tau] (f64) ---- */
__global__ __launch_bounds__(256) void k_mean_sd(const float* __restrict__ signal,
                                                 double* __restrict__ sd) {
    const double c1 = 2.0 * 1.602176563e-19 * 50000000000.0;                   /* 2*Q*BITRATE */
    const double c2 = 4.0 * 1.3806488e-23 * 300.0 * 50000000000.0 / 1000000.0; /* 4kTB/R */
    const double DARK = 1e-10;
    const int wave = threadIdx.x >> 6;
    const int lane = threadIdx.x & 63;
    const int tau = blockIdx.x * 4 + wave;
    if (tau >= TAU) return;
    double m = 0.0;
    if (tau >= 4) {
        const float* p = signal + (size_t)(tau - 4) * BATCH;
        double ssum = 0.0;
        #pragma unroll
        for (int i = 0; i < 8; ++i) ssum += (double)p[lane + 64 * i];
        for (int off = 32; off > 0; off >>= 1) ssum += __shfl_down(ssum, off, 64);
        m = ssum / 512.0;   /* valid on lane 0 */
    }
    if (lane == 0) sd[tau] = sqrt(c1 * (m + DARK) + c2);
}

/* ---- K2: transpose noise (512, TAU) -> noiseT (TAU, 512) ---- */
__global__ __launch_bounds__(256) void k_transpose(const float* __restrict__ noise,
                                                   float* __restrict__ noiseT) {
    __shared__ float tile[32][33];
    const int tt = blockIdx.x * 32;  /* tau0 */
    const int tb = blockIdx.y * 32;  /* b0   */
    const int x = threadIdx.x;       /* 0..31 */
    const int y = threadIdx.y;       /* 0..7  */
    #pragma unroll
    for (int i = 0; i < 4; ++i) {
        const int b = tb + y + 8 * i;
        const int t = tt + x;
        tile[y + 8 * i][x] = (t < TAU) ? noise[(size_t)b * TAU + t] : 0.0f;
    }
    __syncthreads();
    #pragma unroll
    for (int i = 0; i < 4; ++i) {
        const int t = tt + y + 8 * i;
        const int b = tb + x;
        if (t < TAU) noiseT[(size_t)t * BATCH + b] = tile[x][y + 8 * i];
    }
}

/* ---- K3: chunk-local FIR + zero-init IIR; emits s (f32, into d_out) and
        per-chunk end states p_end (f64) ---- */
__global__ __launch_bounds__(512) void k_chunk(const float* __restrict__ signal,
                                               const float* __restrict__ noiseT,
                                               const double* __restrict__ sd,
                                               const Coefs k,
                                               float* __restrict__ sbuf,
                                               double* __restrict__ pend) {
    const int b = threadIdx.x;
    const int c = blockIdx.x;
    const int t0 = c * CHLEN;

    auto XN = [&](int tau) -> double {
        const double sig = (tau >= 4) ? (double)signal[(size_t)(tau - 4) * BATCH + b] : 0.0;
        return sd[tau] * (double)noiseT[(size_t)tau * BATCH + b] + sig;
    };

    double w0 = XN(t0), w1 = XN(t0 + 1), w2 = XN(t0 + 2), w3 = XN(t0 + 3), w4;
    double z0 = 0.0, z1 = 0.0, z2 = 0.0, z3 = 0.0;

    for (int i = 0; i < CHLEN; ++i) {
        const int t = t0 + i;
        w4 = XN(t + 4);
        const double s = k.b0 * w0 + k.b1 * w1 + k.b2 * w2 + k.b3 * w3 + k.b4 * w4;
        sbuf[(size_t)t * BATCH + b] = (float)s;
        double y;
        if (c == 0 && t < 5) y = s;                       /* passthrough head */
        else y = s - (k.c0 * z0 + k.c1 * z1 + k.c2 * z2 + k.c3 * z3);
        z0 = z1; z1 = z2; z2 = z3; z3 = y;
        w0 = w1; w1 = w2; w2 = w3; w3 = w4;
    }
    pend[(size_t)(c * 4 + 0) * BATCH + b] = z0;
    pend[(size_t)(c * 4 + 1) * BATCH + b] = z1;
    pend[(size_t)(c * 4 + 2) * BATCH + b] = z2;
    pend[(size_t)(c * 4 + 3) * BATCH + b] = z3;
}

/* ---- K4: serial cross-chunk fix-up: y0(c+1) = p_end(c) + A^L * y0(c) ---- */
__global__ __launch_bounds__(512) void k_fixup(const Coefs k,
                                               const double* __restrict__ pend,
                                               double* __restrict__ y0) {
    __shared__ double M[4][4];   /* M[j][i] = end-state i given init e_j */
    const int tid = threadIdx.x;
    if (tid < 4) {
        double z0 = (tid == 0) ? 1.0 : 0.0, z1 = (tid == 1) ? 1.0 : 0.0;
        double z2 = (tid == 2) ? 1.0 : 0.0, z3 = (tid == 3) ? 1.0 : 0.0;
        for (int i = 0; i < CHLEN; ++i) {
            const double y = -(k.c0 * z0 + k.c1 * z1 + k.c2 * z2 + k.c3 * z3);
            z0 = z1; z1 = z2; z2 = z3; z3 = y;
        }
        M[tid][0] = z0; M[tid][1] = z1; M[tid][2] = z2; M[tid][3] = z3;
    }
    __syncthreads();
    const double m00 = M[0][0], m01 = M[0][1], m02 = M[0][2], m03 = M[0][3];
    const double m10 = M[1][0], m11 = M[1][1], m12 = M[1][2], m13 = M[1][3];
    const double m20 = M[2][0], m21 = M[2][1], m22 = M[2][2], m23 = M[2][3];
    const double m30 = M[3][0], m31 = M[3][1], m32 = M[3][2], m33 = M[3][3];
    const int b = tid;
    double z0 = pend[(size_t)(0 * 4 + 0) * BATCH + b];
    double z1 = pend[(size_t)(0 * 4 + 1) * BATCH + b];
    double z2 = pend[(size_t)(0 * 4 + 2) * BATCH + b];
    double z3 = pend[(size_t)(0 * 4 + 3) * BATCH + b];
    y0[(size_t)(1 * 4 + 0) * BATCH + b] = z0;
    y0[(size_t)(1 * 4 + 1) * BATCH + b] = z1;
    y0[(size_t)(1 * 4 + 2) * BATCH + b] = z2;
    y0[(size_t)(1 * 4 + 3) * BATCH + b] = z3;
    for (int c = 1; c < NCHUNK - 1; ++c) {
        const double p0 = pend[(size_t)(c * 4 + 0) * BATCH + b];
        const double p1 = pend[(size_t)(c * 4 + 1) * BATCH + b];
        const double p2 = pend[(size_t)(c * 4 + 2) * BATCH + b];
        const double p3 = pend[(size_t)(c * 4 + 3) * BATCH + b];
        const double n0 = p0 + m00 * z0 + m10 * z1 + m20 * z2 + m30 * z3;
        const double n1 = p1 + m01 * z0 + m11 * z1 + m21 * z2 + m31 * z3;
        const double n2 = p2 + m02 * z0 + m12 * z1 + m22 * z2 + m32 * z3;
        const double n3 = p3 + m03 * z0 + m13 * z1 + m23 * z2 + m33 * z3;
        z0 = n0; z1 = n1; z2 = n2; z3 = n3;
        y0[(size_t)((c + 1) * 4 + 0) * BATCH + b] = z0;
        y0[(size_t)((c + 1) * 4 + 1) * BATCH + b] = z1;
        y0[(size_t)((c + 1) * 4 + 2) * BATCH + b] = z2;
        y0[(size_t)((c + 1) * 4 + 3) * BATCH + b] = z3;
    }
}

/* ---- K5: replay each chunk with correct init; in-place s -> y in d_out ---- */
__global__ __launch_bounds__(512) void k_final(const float* __restrict__ sbuf,
                                               const Coefs k,
                                               const double* __restrict__ y0arr,
                                               float* __restrict__ out) {
    const int b = threadIdx.x;
    const int c = blockIdx.x;
    const int t0 = c * CHLEN;
    double z0, z1, z2, z3;
    if (c == 0) { z0 = z1 = z2 = z3 = 0.0; }
    else {
        z0 = y0arr[(size_t)(c * 4 + 0) * BATCH + b];
        z1 = y0arr[(size_t)(c * 4 + 1) * BATCH + b];
        z2 = y0arr[(size_t)(c * 4 + 2) * BATCH + b];
        z3 = y0arr[(size_t)(c * 4 + 3) * BATCH + b];
    }
    for (int i = 0; i < CHLEN; ++i) {
        const int t = t0 + i;
        const double s = (double)sbuf[(size_t)t * BATCH + b];
        double y;
        if (c == 0 && t < 5) y = s;
        else y = s - (k.c0 * z0 + k.c1 * z1 + k.c2 * z2 + k.c3 * z3);
        z0 = z1; z1 = z2; z2 = z3; z3 = y;
        out[(size_t)t * BATCH + b] = (float)y;
    }
}

/* ---- host: replicate _butter_lowpass exactly (f64, same algorithm) ---- */
static Coefs make_coefs() {
    const int order = 4;
    const double wn = 25000000000.0 / (0.5 / 1e-12);     /* 0.05 */
    const double warped = 4.0 * tan(M_PI * wn / 2.0);
    std::complex<double> p[4];
    for (int kk = 1; kk <= order; ++kk)
        p[kk - 1] = warped * std::exp(std::complex<double>(0.0,
                        M_PI * (2 * kk + order - 1) / (2.0 * order)));
    const double gain = warped * warped * warped * warped;
    const double fs2 = 4.0;
    std::complex<double> pz[4], prod(1.0, 0.0);
    for (int i = 0; i < 4; ++i) {
        pz[i] = (fs2 + p[i]) / (fs2 - p[i]);
        prod *= (fs2 - p[i]);
    }
    const double gz = gain * std::real(std::complex<double>(1.0, 0.0) / prod);
    /* a = real(poly(pz)): monic poly from roots via convolution */
    std::complex<double> ac[5] = { {1,0}, {0,0}, {0,0}, {0,0}, {0,0} };
    for (int i = 0; i < 4; ++i)
        for (int j = i + 1; j >= 1; --j)
            ac[j] = ac[j] - pz[i] * ac[j - 1];
    Coefs k;
    k.b0 = gz * 1.0; k.b1 = gz * 4.0; k.b2 = gz * 6.0; k.b3 = gz * 4.0; k.b4 = gz * 1.0;
    /* a_rev = [a4,a3,a2,a1,a0]; coefs = a_rev[:-1] */
    k.c0 = std::real(ac[4]);
    k.c1 = std::real(ac[3]);
    k.c2 = std::real(ac[2]);
    k.c3 = std::real(ac[1]);
    return k;
}

extern "C" void kernel_launch(void* const* d_in, const int* in_sizes, int n_in,
                              void* d_out, int out_size, void* d_ws, size_t ws_size,
                              hipStream_t stream) {
    const float* signal = (const float*)d_in[0];
    const float* noise  = (const float*)d_in[1];
    float* out = (float*)d_out;

    const Coefs k = make_coefs();   /* host f64 math; deterministic each call */

    char* ws = (char*)d_ws;
    double* sd     = (double*)(ws + 0);                      /* 16388*8   = 131104 */
    float*  noiseT = (float*)(ws + 131104);                  /* TAU*512*4 = 33562624 */
    double* pend   = (double*)(ws + 33693728);               /* 256*4*512*8 = 4194304 */
    double* y0     = (double*)(ws + 37888032);               /* 4194304 */
    float*  sbuf   = out;   /* s lives in d_out; K5 reads then overwrites in place */

    hipLaunchKernelGGL(k_mean_sd, dim3(4097), dim3(256), 0, stream, signal, sd);
    hipLaunchKernelGGL(k_transpose, dim3(513, 16), dim3(32, 8), 0, stream, noise, noiseT);
    hipLaunchKernelGGL(k_chunk, dim3(NCHUNK), dim3(512), 0, stream,
                       signal, noiseT, sd, k, sbuf, pend);
    hipLaunchKernelGGL(k_fixup, dim3(1), dim3(512), 0, stream, k, pend, y0);
    hipLaunchKernelGGL(k_final, dim3(NCHUNK), dim3(512), 0, stream, sbuf, k, y0, out);
}

// Round 3
// 84.647 us; speedup vs baseline: 2.6570x; 2.6570x over previous
//
#include <hip/hip_runtime.h>
#include <math.h>
#include <complex>

#define T_STEPS 16384
#define BATCH   512
#define KF      5
#define TAU     (T_STEPS + KF - 1)   /* 16388 */
#define NCHUNK  256
#define CHLEN   (T_STEPS / NCHUNK)   /* 64 */
#define NSER    6                    /* truncated Neumann series terms: ||M^5||~5e-9 */

struct Coefs {
    double b0, b1, b2, b3, b4;   /* FIR numerator */
    double c0, c1, c2, c3;       /* a_rev[:-1] = [a4,a3,a2,a1] */
};
struct Mats {
    double m[NSER - 1][16];      /* M^1..M^5, layout m[d][j*4+i]: init j -> end i */
};

/* ---- K1: per-tau batch mean of padded signal -> noise_sd[tau] (f64) ---- */
__global__ __launch_bounds__(256) void k_mean_sd(const float* __restrict__ signal,
                                                 double* __restrict__ sd) {
    const double c1 = 2.0 * 1.602176563e-19 * 50000000000.0;                   /* 2*Q*BITRATE */
    const double c2 = 4.0 * 1.3806488e-23 * 300.0 * 50000000000.0 / 1000000.0; /* 4kTB/R */
    const double DARK = 1e-10;
    const int wave = threadIdx.x >> 6;
    const int lane = threadIdx.x & 63;
    const int tau = blockIdx.x * 4 + wave;
    if (tau >= TAU) return;
    double m = 0.0;
    if (tau >= 4) {
        const float* p = signal + (size_t)(tau - 4) * BATCH;
        double ssum = 0.0;
        #pragma unroll
        for (int i = 0; i < 8; ++i) ssum += (double)p[lane + 64 * i];
        for (int off = 32; off > 0; off >>= 1) ssum += __shfl_down(ssum, off, 64);
        m = ssum / 512.0;   /* valid on lane 0 */
    }
    if (lane == 0) sd[tau] = sqrt(c1 * (m + DARK) + c2);
}

/* ---- K2: transpose noise (512, TAU) -> noiseT (TAU, 512) ---- */
__global__ __launch_bounds__(256) void k_transpose(const float* __restrict__ noise,
                                                   float* __restrict__ noiseT) {
    __shared__ float tile[32][33];
    const int tt = blockIdx.x * 32;  /* tau0 */
    const int tb = blockIdx.y * 32;  /* b0   */
    const int x = threadIdx.x;       /* 0..31 */
    const int y = threadIdx.y;       /* 0..7  */
    #pragma unroll
    for (int i = 0; i < 4; ++i) {
        const int b = tb + y + 8 * i;
        const int t = tt + x;
        tile[y + 8 * i][x] = (t < TAU) ? noise[(size_t)b * TAU + t] : 0.0f;
    }
    __syncthreads();
    #pragma unroll
    for (int i = 0; i < 4; ++i) {
        const int t = tt + y + 8 * i;
        const int b = tb + x;
        if (t < TAU) noiseT[(size_t)t * BATCH + b] = tile[x][y + 8 * i];
    }
}

/* ---- K3: chunk-local FIR + zero-init IIR; emits s (f32, into d_out) and
        per-chunk end states p_end (f64) ---- */
__global__ __launch_bounds__(512) void k_chunk(const float* __restrict__ signal,
                                               const float* __restrict__ noiseT,
                                               const double* __restrict__ sd,
                                               const Coefs k,
                                               float* __restrict__ sbuf,
                                               double* __restrict__ pend) {
    const int b = threadIdx.x;
    const int c = blockIdx.x;
    const int t0 = c * CHLEN;

    auto XN = [&](int tau) -> double {
        const double sig = (tau >= 4) ? (double)signal[(size_t)(tau - 4) * BATCH + b] : 0.0;
        return sd[tau] * (double)noiseT[(size_t)tau * BATCH + b] + sig;
    };

    double w0 = XN(t0), w1 = XN(t0 + 1), w2 = XN(t0 + 2), w3 = XN(t0 + 3), w4;
    double z0 = 0.0, z1 = 0.0, z2 = 0.0, z3 = 0.0;

    for (int i = 0; i < CHLEN; ++i) {
        const int t = t0 + i;
        w4 = XN(t + 4);
        const double s = k.b0 * w0 + k.b1 * w1 + k.b2 * w2 + k.b3 * w3 + k.b4 * w4;
        sbuf[(size_t)t * BATCH + b] = (float)s;
        double y;
        if (c == 0 && t < 5) y = s;                       /* passthrough head */
        else y = s - (k.c0 * z0 + k.c1 * z1 + k.c2 * z2 + k.c3 * z3);
        z0 = z1; z1 = z2; z2 = z3; z3 = y;
        w0 = w1; w1 = w2; w2 = w3; w3 = w4;
    }
    pend[(size_t)(c * 4 + 0) * BATCH + b] = z0;
    pend[(size_t)(c * 4 + 1) * BATCH + b] = z1;
    pend[(size_t)(c * 4 + 2) * BATCH + b] = z2;
    pend[(size_t)(c * 4 + 3) * BATCH + b] = z3;
}

/* ---- K5: init from truncated series over neighbor pend, then replay ----
   y0(c) = sum_{d=1..min(c,NSER)} M^{d-1} * pend(c-d);  ||M^5|| ~ 5e-9. */
__global__ __launch_bounds__(512) void k_final(const float* __restrict__ sbuf,
                                               const Coefs k,
                                               const Mats mats,
                                               const double* __restrict__ pend,
                                               float* __restrict__ out) {
    const int b = threadIdx.x;
    const int c = blockIdx.x;
    const int t0 = c * CHLEN;

    double z0 = 0.0, z1 = 0.0, z2 = 0.0, z3 = 0.0;
    #pragma unroll
    for (int d = 1; d <= NSER; ++d) {
        if (d <= c) {
            const int j = c - d;
            const double p0 = pend[(size_t)(j * 4 + 0) * BATCH + b];
            const double p1 = pend[(size_t)(j * 4 + 1) * BATCH + b];
            const double p2 = pend[(size_t)(j * 4 + 2) * BATCH + b];
            const double p3 = pend[(size_t)(j * 4 + 3) * BATCH + b];
            if (d == 1) {
                z0 += p0; z1 += p1; z2 += p2; z3 += p3;
            } else {
                const double* m = mats.m[d - 2];
                z0 += p0 * m[0]  + p1 * m[4]  + p2 * m[8]  + p3 * m[12];
                z1 += p0 * m[1]  + p1 * m[5]  + p2 * m[9]  + p3 * m[13];
                z2 += p0 * m[2]  + p1 * m[6]  + p2 * m[10] + p3 * m[14];
                z3 += p0 * m[3]  + p1 * m[7]  + p2 * m[11] + p3 * m[15];
            }
        }
    }

    for (int i = 0; i < CHLEN; ++i) {
        const int t = t0 + i;
        const double s = (double)sbuf[(size_t)t * BATCH + b];
        double y;
        if (c == 0 && t < 5) y = s;
        else y = s - (k.c0 * z0 + k.c1 * z1 + k.c2 * z2 + k.c3 * z3);
        z0 = z1; z1 = z2; z2 = z3; z3 = y;
        out[(size_t)t * BATCH + b] = (float)y;
    }
}

/* ---- host: replicate _butter_lowpass exactly (f64, same algorithm) ---- */
static Coefs make_coefs() {
    const int order = 4;
    const double wn = 25000000000.0 / (0.5 / 1e-12);     /* 0.05 */
    const double warped = 4.0 * tan(M_PI * wn / 2.0);
    std::complex<double> p[4];
    for (int kk = 1; kk <= order; ++kk)
        p[kk - 1] = warped * std::exp(std::complex<double>(0.0,
                        M_PI * (2 * kk + order - 1) / (2.0 * order)));
    const double gain = warped * warped * warped * warped;
    const double fs2 = 4.0;
    std::complex<double> pz[4], prod(1.0, 0.0);
    for (int i = 0; i < 4; ++i) {
        pz[i] = (fs2 + p[i]) / (fs2 - p[i]);
        prod *= (fs2 - p[i]);
    }
    const double gz = gain * std::real(std::complex<double>(1.0, 0.0) / prod);
    std::complex<double> ac[5] = { {1,0}, {0,0}, {0,0}, {0,0}, {0,0} };
    for (int i = 0; i < 4; ++i)
        for (int j = i + 1; j >= 1; --j)
            ac[j] = ac[j] - pz[i] * ac[j - 1];
    Coefs k;
    k.b0 = gz * 1.0; k.b1 = gz * 4.0; k.b2 = gz * 6.0; k.b3 = gz * 4.0; k.b4 = gz * 1.0;
    k.c0 = std::real(ac[4]);
    k.c1 = std::real(ac[3]);
    k.c2 = std::real(ac[2]);
    k.c3 = std::real(ac[1]);
    return k;
}

/* compose(P,Q)[j][i] = sum_k P[j*4+k] * Q[k*4+i]  ("apply P then Q") */
static void mat_compose(const double* P, const double* Q, double* R) {
    double t[16];
    for (int j = 0; j < 4; ++j)
        for (int i = 0; i < 4; ++i) {
            double s = 0.0;
            for (int kk = 0; kk < 4; ++kk) s += P[j * 4 + kk] * Q[kk * 4 + i];
            t[j * 4 + i] = s;
        }
    for (int i = 0; i < 16; ++i) R[i] = t[i];
}

static Mats make_mats(const Coefs& k) {
    /* step matrix S[j][i]: end0=z1, end1=z2, end2=z3, end3=-(c0 z0+c1 z1+c2 z2+c3 z3) */
    double S[16] = {0};
    S[1 * 4 + 0] = 1.0;
    S[2 * 4 + 1] = 1.0;
    S[3 * 4 + 2] = 1.0;
    S[0 * 4 + 3] = -k.c0;
    S[1 * 4 + 3] = -k.c1;
    S[2 * 4 + 3] = -k.c2;
    S[3 * 4 + 3] = -k.c3;
    /* M = S^CHLEN */
    double M[16] = {1,0,0,0, 0,1,0,0, 0,0,1,0, 0,0,0,1};
    for (int i = 0; i < CHLEN; ++i) mat_compose(M, S, M);
    Mats mm;
    for (int i = 0; i < 16; ++i) mm.m[0][i] = M[i];
    for (int d = 1; d < NSER - 1; ++d) mat_compose(mm.m[d - 1], M, mm.m[d]);
    return mm;
}

extern "C" void kernel_launch(void* const* d_in, const int* in_sizes, int n_in,
                              void* d_out, int out_size, void* d_ws, size_t ws_size,
                              hipStream_t stream) {
    const float* signal = (const float*)d_in[0];
    const float* noise  = (const float*)d_in[1];
    float* out = (float*)d_out;

    const Coefs k = make_coefs();   /* host f64 math; deterministic each call */
    const Mats  mm = make_mats(k);

    char* ws = (char*)d_ws;
    double* sd     = (double*)(ws + 0);                      /* 16388*8   = 131104 */
    float*  noiseT = (float*)(ws + 131104);                  /* TAU*512*4 = 33562624 */
    double* pend   = (double*)(ws + 33693728);               /* 256*4*512*8 = 4194304 */
    float*  sbuf   = out;   /* s lives in d_out; k_final reads then overwrites in place */

    hipLaunchKernelGGL(k_mean_sd, dim3(4097), dim3(256), 0, stream, signal, sd);
    hipLaunchKernelGGL(k_transpose, dim3(513, 16), dim3(32, 8), 0, stream, noise, noiseT);
    hipLaunchKernelGGL(k_chunk, dim3(NCHUNK), dim3(512), 0, stream,
                       signal, noiseT, sd, k, sbuf, pend);
    hipLaunchKernelGGL(k_final, dim3(NCHUNK), dim3(512), 0, stream, sbuf, k, mm, pend, out);
}